// Round 3
// baseline (128.898 us; speedup 1.0000x reference)
//
#include <hip/hip_runtime.h>
#include <math.h>

#define NATOMS 512
#define TPB 256
#define WPB 4  // elements (waves) per block
#define FPE (3 * NATOMS)      // floats per element per array = 1536
#define F4PE (FPE / 4)        // float4 per element = 384

// Block of 256 threads handles 4 batch elements.
// Phase 1: coalesced float4 staging of src+dst (4 elems x 6 KB x 2 = 48 KB) into LDS.
//          Lane stride 16 B -> minimum-transaction streaming from HBM/L2.
// Phase 2: wave w reduces element w. Lane l handles atoms l+64k (k=0..7); LDS reads
//          at 12 B lane stride -> bank 3l%32, 2 lanes/bank = conflict-free on wave64.
// Single pass: uncentered sums + centroid correction afterwards:
//   R = Sum(s d^T) - (Sum s)(Sum d)^T / n
//   sq = Sum|s|^2+|d|^2 - (|Sum s|^2+|Sum d|^2)/n
// Analytic 3x3 eigen-solve of R^T R (double) on lane 0.
__global__ __launch_bounds__(TPB) void kabsch_rmsd_kernel(
    const float* __restrict__ inp,
    const float* __restrict__ tgt,
    const int* __restrict__ num_atoms,
    float* __restrict__ out,
    int B)
{
    __shared__ float sS[WPB * FPE];
    __shared__ float sD[WPB * FPE];

    const int t = threadIdx.x;
    const int wave = t >> 6;
    const int lane = t & 63;

    // ---- Phase 1: coalesced staging ----
    {
        const size_t blk_f4 = (size_t)blockIdx.x * (WPB * F4PE);
        const size_t lim_f4 = (size_t)B * F4PE;
        const float4* gs = (const float4*)inp;
        const float4* gd = (const float4*)tgt;
        float4* ls = (float4*)sS;
        float4* ld = (float4*)sD;
        #pragma unroll
        for (int i = 0; i < WPB * F4PE / TPB; ++i) {   // 6 iterations
            const int loc = t + TPB * i;
            const size_t g = blk_f4 + loc;
            if (g < lim_f4) {
                ls[loc] = gs[g];
                ld[loc] = gd[g];
            }
        }
    }
    __syncthreads();

    // ---- Phase 2: per-wave reduction ----
    const int b = blockIdx.x * WPB + wave;
    if (b >= B) return;
    const int na = num_atoms[b];

    const float* eS = sS + wave * FPE;
    const float* eD = sD + wave * FPE;

    float v[16];
    #pragma unroll
    for (int i = 0; i < 16; ++i) v[i] = 0.f;

    #pragma unroll
    for (int k = 0; k < 8; ++k) {
        const int atom = lane + 64 * k;
        const int off = 3 * atom;
        const float m = (atom < na) ? 1.f : 0.f;
        const float sx = eS[off]     * m;
        const float sy = eS[off + 1] * m;
        const float sz = eS[off + 2] * m;
        const float dx = eD[off]     * m;
        const float dy = eD[off + 1] * m;
        const float dz = eD[off + 2] * m;
        v[0]  += sx * dx;  v[1]  += sx * dy;  v[2]  += sx * dz;
        v[3]  += sy * dx;  v[4]  += sy * dy;  v[5]  += sy * dz;
        v[6]  += sz * dx;  v[7]  += sz * dy;  v[8]  += sz * dz;
        v[9]  += sx;  v[10] += sy;  v[11] += sz;
        v[12] += dx;  v[13] += dy;  v[14] += dz;
        v[15] += sx * sx + sy * sy + sz * sz + dx * dx + dy * dy + dz * dz;
    }

    // 64-lane butterfly reduction (no barrier needed)
    #pragma unroll
    for (int i = 0; i < 16; ++i) {
        #pragma unroll
        for (int mask = 32; mask > 0; mask >>= 1) {
            v[i] += __shfl_xor(v[i], mask);
        }
    }

    if (lane == 0) {
        const double n = (double)na;
        const double sx = (double)v[9],  sy = (double)v[10], sz = (double)v[11];
        const double tx = (double)v[12], ty = (double)v[13], tz = (double)v[14];

        double R[3][3];
        R[0][0] = (double)v[0] - sx * tx / n;
        R[0][1] = (double)v[1] - sx * ty / n;
        R[0][2] = (double)v[2] - sx * tz / n;
        R[1][0] = (double)v[3] - sy * tx / n;
        R[1][1] = (double)v[4] - sy * ty / n;
        R[1][2] = (double)v[5] - sy * tz / n;
        R[2][0] = (double)v[6] - sz * tx / n;
        R[2][1] = (double)v[7] - sz * ty / n;
        R[2][2] = (double)v[8] - sz * tz / n;

        const double sq = (double)v[15] - (sx * sx + sy * sy + sz * sz
                                         + tx * tx + ty * ty + tz * tz) / n;

        const double detR =
            R[0][0] * (R[1][1] * R[2][2] - R[1][2] * R[2][1])
          - R[0][1] * (R[1][0] * R[2][2] - R[1][2] * R[2][0])
          + R[0][2] * (R[1][0] * R[2][1] - R[1][1] * R[2][0]);

        double A00 = R[0][0]*R[0][0] + R[1][0]*R[1][0] + R[2][0]*R[2][0];
        double A11 = R[0][1]*R[0][1] + R[1][1]*R[1][1] + R[2][1]*R[2][1];
        double A22 = R[0][2]*R[0][2] + R[1][2]*R[1][2] + R[2][2]*R[2][2];
        double A01 = R[0][0]*R[0][1] + R[1][0]*R[1][1] + R[2][0]*R[2][1];
        double A02 = R[0][0]*R[0][2] + R[1][0]*R[1][2] + R[2][0]*R[2][2];
        double A12 = R[0][1]*R[0][2] + R[1][1]*R[1][2] + R[2][1]*R[2][2];

        double e0, e1, e2;  // descending
        const double p1 = A01*A01 + A02*A02 + A12*A12;
        if (p1 < 1e-30) {
            e0 = A00; e1 = A11; e2 = A22;
            double tmp;
            if (e0 < e1) { tmp = e0; e0 = e1; e1 = tmp; }
            if (e1 < e2) { tmp = e1; e1 = e2; e2 = tmp; }
            if (e0 < e1) { tmp = e0; e0 = e1; e1 = tmp; }
        } else {
            const double q  = (A00 + A11 + A22) / 3.0;
            const double b00 = A00 - q, b11 = A11 - q, b22 = A22 - q;
            const double p2 = b00*b00 + b11*b11 + b22*b22 + 2.0 * p1;
            const double p  = sqrt(p2 / 6.0);
            const double ip = 1.0 / p;
            const double B00 = b00*ip, B11 = b11*ip, B22 = b22*ip;
            const double B01 = A01*ip, B02 = A02*ip, B12 = A12*ip;
            double r = 0.5 * (B00 * (B11 * B22 - B12 * B12)
                            - B01 * (B01 * B22 - B12 * B02)
                            + B02 * (B01 * B12 - B11 * B02));
            if (r < -1.0) r = -1.0;
            if (r >  1.0) r =  1.0;
            const double phi = acos(r) / 3.0;
            e0 = q + 2.0 * p * cos(phi);
            e2 = q + 2.0 * p * cos(phi + 2.0943951023931953);  // +2pi/3
            e1 = 3.0 * q - e0 - e2;
        }

        const double S0 = sqrt(e0 > 0.0 ? e0 : 0.0);
        const double S1 = sqrt(e1 > 0.0 ? e1 : 0.0);
        const double S2 = sqrt(e2 > 0.0 ? e2 : 0.0);
        const double dsgn = (detR > 0.0) ? 1.0 : ((detR < 0.0) ? -1.0 : 0.0);
        const double trace_opt = S0 + S1 + dsgn * S2;

        double msd = (sq - 2.0 * trace_opt) / n;
        if (msd < 0.0) msd = 0.0;
        out[b] = (float)sqrt(msd);
    }
}

extern "C" void kernel_launch(void* const* d_in, const int* in_sizes, int n_in,
                              void* d_out, int out_size, void* d_ws, size_t ws_size,
                              hipStream_t stream) {
    const float* inp = (const float*)d_in[0];
    const float* tgt = (const float*)d_in[1];
    const int* num_atoms = (const int*)d_in[2];
    float* out = (float*)d_out;

    const int B = in_sizes[0] / FPE;
    const int blocks = (B + WPB - 1) / WPB;
    kabsch_rmsd_kernel<<<blocks, TPB, 0, stream>>>(inp, tgt, num_atoms, out, B);
}

// Round 4
// 122.143 us; speedup vs baseline: 1.0553x; 1.0553x over previous
//
#include <hip/hip_runtime.h>
#include <math.h>

#define NATOMS 512
#define TPB 256
#define WPB 4  // waves per block; one wave handles one batch element
#define FPE (3 * NATOMS)

// ---------------- Kernel 1: streaming reduction ----------------
// One 64-lane wave per batch element. Lane l handles atoms [8l, 8l+8) :
// floats [24l, 24l+24) = 6 consecutive float4 loads per array.
// Accumulates 16 uncentered sums, butterfly-reduces, writes them to ws.
__global__ __launch_bounds__(TPB) void kabsch_reduce_kernel(
    const float* __restrict__ inp,
    const float* __restrict__ tgt,
    const int* __restrict__ num_atoms,
    float* __restrict__ partial,   // [B][16]
    int B)
{
    const int wave = threadIdx.x >> 6;
    const int lane = threadIdx.x & 63;
    const int b = blockIdx.x * WPB + wave;
    if (b >= B) return;

    const int na = num_atoms[b];

    const float4* s4 = (const float4*)(inp + (size_t)b * FPE) + 6 * lane;
    const float4* d4 = (const float4*)(tgt + (size_t)b * FPE) + 6 * lane;

    union U { float4 q[6]; float f[24]; };
    U S, D;
    #pragma unroll
    for (int i = 0; i < 6; ++i) S.q[i] = s4[i];
    #pragma unroll
    for (int i = 0; i < 6; ++i) D.q[i] = d4[i];

    float v[16];
    #pragma unroll
    for (int i = 0; i < 16; ++i) v[i] = 0.f;

    const int base = lane * 8;
    #pragma unroll
    for (int k = 0; k < 8; ++k) {
        const float m = (base + k < na) ? 1.f : 0.f;
        const float sx = S.f[3 * k]     * m;
        const float sy = S.f[3 * k + 1] * m;
        const float sz = S.f[3 * k + 2] * m;
        const float dx = D.f[3 * k]     * m;
        const float dy = D.f[3 * k + 1] * m;
        const float dz = D.f[3 * k + 2] * m;
        v[0]  += sx * dx;  v[1]  += sx * dy;  v[2]  += sx * dz;
        v[3]  += sy * dx;  v[4]  += sy * dy;  v[5]  += sy * dz;
        v[6]  += sz * dx;  v[7]  += sz * dy;  v[8]  += sz * dz;
        v[9]  += sx;  v[10] += sy;  v[11] += sz;
        v[12] += dx;  v[13] += dy;  v[14] += dz;
        v[15] += sx * sx + sy * sy + sz * sz + dx * dx + dy * dy + dz * dz;
    }

    // 64-lane butterfly reduction (total lands in every lane)
    #pragma unroll
    for (int i = 0; i < 16; ++i) {
        #pragma unroll
        for (int mask = 32; mask > 0; mask >>= 1) {
            v[i] += __shfl_xor(v[i], mask);
        }
    }

    if (lane == 0) {
        float4* p = (float4*)(partial + (size_t)b * 16);
        p[0] = make_float4(v[0],  v[1],  v[2],  v[3]);
        p[1] = make_float4(v[4],  v[5],  v[6],  v[7]);
        p[2] = make_float4(v[8],  v[9],  v[10], v[11]);
        p[3] = make_float4(v[12], v[13], v[14], v[15]);
    }
}

// ---------------- Kernel 2: per-element epilogue ----------------
// One thread per batch element; fully parallel f64 Cardano eigen-solve.
__global__ __launch_bounds__(TPB) void kabsch_epilogue_kernel(
    const float* __restrict__ partial,
    const int* __restrict__ num_atoms,
    float* __restrict__ out,
    int B)
{
    const int b = blockIdx.x * TPB + threadIdx.x;
    if (b >= B) return;

    const float4* p = (const float4*)(partial + (size_t)b * 16);
    const float4 r0 = p[0], r1 = p[1], r2 = p[2], r3 = p[3];
    float v[16] = { r0.x, r0.y, r0.z, r0.w,
                    r1.x, r1.y, r1.z, r1.w,
                    r2.x, r2.y, r2.z, r2.w,
                    r3.x, r3.y, r3.z, r3.w };

    const int na = num_atoms[b];
    const double n = (double)na;
    const double sx = (double)v[9],  sy = (double)v[10], sz = (double)v[11];
    const double tx = (double)v[12], ty = (double)v[13], tz = (double)v[14];

    double R[3][3];
    R[0][0] = (double)v[0] - sx * tx / n;
    R[0][1] = (double)v[1] - sx * ty / n;
    R[0][2] = (double)v[2] - sx * tz / n;
    R[1][0] = (double)v[3] - sy * tx / n;
    R[1][1] = (double)v[4] - sy * ty / n;
    R[1][2] = (double)v[5] - sy * tz / n;
    R[2][0] = (double)v[6] - sz * tx / n;
    R[2][1] = (double)v[7] - sz * ty / n;
    R[2][2] = (double)v[8] - sz * tz / n;

    const double sq = (double)v[15] - (sx * sx + sy * sy + sz * sz
                                     + tx * tx + ty * ty + tz * tz) / n;

    const double detR =
        R[0][0] * (R[1][1] * R[2][2] - R[1][2] * R[2][1])
      - R[0][1] * (R[1][0] * R[2][2] - R[1][2] * R[2][0])
      + R[0][2] * (R[1][0] * R[2][1] - R[1][1] * R[2][0]);

    double A00 = R[0][0]*R[0][0] + R[1][0]*R[1][0] + R[2][0]*R[2][0];
    double A11 = R[0][1]*R[0][1] + R[1][1]*R[1][1] + R[2][1]*R[2][1];
    double A22 = R[0][2]*R[0][2] + R[1][2]*R[1][2] + R[2][2]*R[2][2];
    double A01 = R[0][0]*R[0][1] + R[1][0]*R[1][1] + R[2][0]*R[2][1];
    double A02 = R[0][0]*R[0][2] + R[1][0]*R[1][2] + R[2][0]*R[2][2];
    double A12 = R[0][1]*R[0][2] + R[1][1]*R[1][2] + R[2][1]*R[2][2];

    double e0, e1, e2;  // descending
    const double p1 = A01*A01 + A02*A02 + A12*A12;
    if (p1 < 1e-30) {
        e0 = A00; e1 = A11; e2 = A22;
        double tmp;
        if (e0 < e1) { tmp = e0; e0 = e1; e1 = tmp; }
        if (e1 < e2) { tmp = e1; e1 = e2; e2 = tmp; }
        if (e0 < e1) { tmp = e0; e0 = e1; e1 = tmp; }
    } else {
        const double q  = (A00 + A11 + A22) / 3.0;
        const double b00 = A00 - q, b11 = A11 - q, b22 = A22 - q;
        const double p2 = b00*b00 + b11*b11 + b22*b22 + 2.0 * p1;
        const double pp = sqrt(p2 / 6.0);
        const double ip = 1.0 / pp;
        const double B00 = b00*ip, B11 = b11*ip, B22 = b22*ip;
        const double B01 = A01*ip, B02 = A02*ip, B12 = A12*ip;
        double r = 0.5 * (B00 * (B11 * B22 - B12 * B12)
                        - B01 * (B01 * B22 - B12 * B02)
                        + B02 * (B01 * B12 - B11 * B02));
        if (r < -1.0) r = -1.0;
        if (r >  1.0) r =  1.0;
        const double phi = acos(r) / 3.0;
        e0 = q + 2.0 * pp * cos(phi);
        e2 = q + 2.0 * pp * cos(phi + 2.0943951023931953);  // +2pi/3
        e1 = 3.0 * q - e0 - e2;
    }

    const double S0 = sqrt(e0 > 0.0 ? e0 : 0.0);
    const double S1 = sqrt(e1 > 0.0 ? e1 : 0.0);
    const double S2 = sqrt(e2 > 0.0 ? e2 : 0.0);
    const double dsgn = (detR > 0.0) ? 1.0 : ((detR < 0.0) ? -1.0 : 0.0);
    const double trace_opt = S0 + S1 + dsgn * S2;

    double msd = (sq - 2.0 * trace_opt) / n;
    if (msd < 0.0) msd = 0.0;
    out[b] = (float)sqrt(msd);
}

extern "C" void kernel_launch(void* const* d_in, const int* in_sizes, int n_in,
                              void* d_out, int out_size, void* d_ws, size_t ws_size,
                              hipStream_t stream) {
    const float* inp = (const float*)d_in[0];
    const float* tgt = (const float*)d_in[1];
    const int* num_atoms = (const int*)d_in[2];
    float* out = (float*)d_out;
    float* partial = (float*)d_ws;  // B*16 floats = 512 KB

    const int B = in_sizes[0] / FPE;
    const int blocks1 = (B + WPB - 1) / WPB;
    kabsch_reduce_kernel<<<blocks1, TPB, 0, stream>>>(inp, tgt, num_atoms, partial, B);
    const int blocks2 = (B + TPB - 1) / TPB;
    kabsch_epilogue_kernel<<<blocks2, TPB, 0, stream>>>(partial, num_atoms, out, B);
}

// Round 5
// 120.168 us; speedup vs baseline: 1.0726x; 1.0164x over previous
//
#include <hip/hip_runtime.h>
#include <math.h>

#define NATOMS 512
#define TPB 256
#define WPB 4  // waves per block; one wave handles one batch element
#define FPE (3 * NATOMS)

// Packed 12-byte atom record; align 4 so addresses base+12*A are valid.
struct __attribute__((aligned(4))) F3 { float x, y, z; };

// ---------------- Kernel 1: streaming reduction ----------------
// One 64-lane wave per batch element. Lane l handles atoms 64k+l (k=0..7),
// loading each atom's 12 B directly: lane stride 12 B -> every load
// instruction covers a contiguous, fully-consumed 768 B (12 cache lines).
// Accumulates 16 uncentered sums, butterfly-reduces, writes to ws.
__global__ __launch_bounds__(TPB) void kabsch_reduce_kernel(
    const float* __restrict__ inp,
    const float* __restrict__ tgt,
    const int* __restrict__ num_atoms,
    float* __restrict__ partial,   // [B][16]
    int B)
{
    const int wave = threadIdx.x >> 6;
    const int lane = threadIdx.x & 63;
    const int b = blockIdx.x * WPB + wave;
    if (b >= B) return;

    const int na = num_atoms[b];

    const F3* sA = (const F3*)(inp + (size_t)b * FPE);
    const F3* dA = (const F3*)(tgt + (size_t)b * FPE);

    // Issue all 16 loads up front (independent, compiler can keep them in flight)
    F3 S[8], D[8];
    #pragma unroll
    for (int k = 0; k < 8; ++k) {
        const int atom = 64 * k + lane;
        S[k] = sA[atom];
        D[k] = dA[atom];
    }

    float v[16];
    #pragma unroll
    for (int i = 0; i < 16; ++i) v[i] = 0.f;

    #pragma unroll
    for (int k = 0; k < 8; ++k) {
        const int atom = 64 * k + lane;
        const float m = (atom < na) ? 1.f : 0.f;
        const float sx = S[k].x * m;
        const float sy = S[k].y * m;
        const float sz = S[k].z * m;
        const float dx = D[k].x * m;
        const float dy = D[k].y * m;
        const float dz = D[k].z * m;
        v[0]  += sx * dx;  v[1]  += sx * dy;  v[2]  += sx * dz;
        v[3]  += sy * dx;  v[4]  += sy * dy;  v[5]  += sy * dz;
        v[6]  += sz * dx;  v[7]  += sz * dy;  v[8]  += sz * dz;
        v[9]  += sx;  v[10] += sy;  v[11] += sz;
        v[12] += dx;  v[13] += dy;  v[14] += dz;
        v[15] += sx * sx + sy * sy + sz * sz + dx * dx + dy * dy + dz * dz;
    }

    // 64-lane butterfly reduction
    #pragma unroll
    for (int i = 0; i < 16; ++i) {
        #pragma unroll
        for (int mask = 32; mask > 0; mask >>= 1) {
            v[i] += __shfl_xor(v[i], mask);
        }
    }

    if (lane == 0) {
        float4* p = (float4*)(partial + (size_t)b * 16);
        p[0] = make_float4(v[0],  v[1],  v[2],  v[3]);
        p[1] = make_float4(v[4],  v[5],  v[6],  v[7]);
        p[2] = make_float4(v[8],  v[9],  v[10], v[11]);
        p[3] = make_float4(v[12], v[13], v[14], v[15]);
    }
}

// ---------------- Kernel 2: per-element epilogue ----------------
// One thread per batch element; fully parallel f64 Cardano eigen-solve.
__global__ __launch_bounds__(TPB) void kabsch_epilogue_kernel(
    const float* __restrict__ partial,
    const int* __restrict__ num_atoms,
    float* __restrict__ out,
    int B)
{
    const int b = blockIdx.x * TPB + threadIdx.x;
    if (b >= B) return;

    const float4* p = (const float4*)(partial + (size_t)b * 16);
    const float4 r0 = p[0], r1 = p[1], r2 = p[2], r3 = p[3];
    float v[16] = { r0.x, r0.y, r0.z, r0.w,
                    r1.x, r1.y, r1.z, r1.w,
                    r2.x, r2.y, r2.z, r2.w,
                    r3.x, r3.y, r3.z, r3.w };

    const int na = num_atoms[b];
    const double n = (double)na;
    const double sx = (double)v[9],  sy = (double)v[10], sz = (double)v[11];
    const double tx = (double)v[12], ty = (double)v[13], tz = (double)v[14];

    double R[3][3];
    R[0][0] = (double)v[0] - sx * tx / n;
    R[0][1] = (double)v[1] - sx * ty / n;
    R[0][2] = (double)v[2] - sx * tz / n;
    R[1][0] = (double)v[3] - sy * tx / n;
    R[1][1] = (double)v[4] - sy * ty / n;
    R[1][2] = (double)v[5] - sy * tz / n;
    R[2][0] = (double)v[6] - sz * tx / n;
    R[2][1] = (double)v[7] - sz * ty / n;
    R[2][2] = (double)v[8] - sz * tz / n;

    const double sq = (double)v[15] - (sx * sx + sy * sy + sz * sz
                                     + tx * tx + ty * ty + tz * tz) / n;

    const double detR =
        R[0][0] * (R[1][1] * R[2][2] - R[1][2] * R[2][1])
      - R[0][1] * (R[1][0] * R[2][2] - R[1][2] * R[2][0])
      + R[0][2] * (R[1][0] * R[2][1] - R[1][1] * R[2][0]);

    double A00 = R[0][0]*R[0][0] + R[1][0]*R[1][0] + R[2][0]*R[2][0];
    double A11 = R[0][1]*R[0][1] + R[1][1]*R[1][1] + R[2][1]*R[2][1];
    double A22 = R[0][2]*R[0][2] + R[1][2]*R[1][2] + R[2][2]*R[2][2];
    double A01 = R[0][0]*R[0][1] + R[1][0]*R[1][1] + R[2][0]*R[2][1];
    double A02 = R[0][0]*R[0][2] + R[1][0]*R[1][2] + R[2][0]*R[2][2];
    double A12 = R[0][1]*R[0][2] + R[1][1]*R[1][2] + R[2][1]*R[2][2];

    double e0, e1, e2;  // descending
    const double p1 = A01*A01 + A02*A02 + A12*A12;
    if (p1 < 1e-30) {
        e0 = A00; e1 = A11; e2 = A22;
        double tmp;
        if (e0 < e1) { tmp = e0; e0 = e1; e1 = tmp; }
        if (e1 < e2) { tmp = e1; e1 = e2; e2 = tmp; }
        if (e0 < e1) { tmp = e0; e0 = e1; e1 = tmp; }
    } else {
        const double q  = (A00 + A11 + A22) / 3.0;
        const double b00 = A00 - q, b11 = A11 - q, b22 = A22 - q;
        const double p2 = b00*b00 + b11*b11 + b22*b22 + 2.0 * p1;
        const double pp = sqrt(p2 / 6.0);
        const double ip = 1.0 / pp;
        const double B00 = b00*ip, B11 = b11*ip, B22 = b22*ip;
        const double B01 = A01*ip, B02 = A02*ip, B12 = A12*ip;
        double r = 0.5 * (B00 * (B11 * B22 - B12 * B12)
                        - B01 * (B01 * B22 - B12 * B02)
                        + B02 * (B01 * B12 - B11 * B02));
        if (r < -1.0) r = -1.0;
        if (r >  1.0) r =  1.0;
        const double phi = acos(r) / 3.0;
        e0 = q + 2.0 * pp * cos(phi);
        e2 = q + 2.0 * pp * cos(phi + 2.0943951023931953);  // +2pi/3
        e1 = 3.0 * q - e0 - e2;
    }

    const double S0 = sqrt(e0 > 0.0 ? e0 : 0.0);
    const double S1 = sqrt(e1 > 0.0 ? e1 : 0.0);
    const double S2 = sqrt(e2 > 0.0 ? e2 : 0.0);
    const double dsgn = (detR > 0.0) ? 1.0 : ((detR < 0.0) ? -1.0 : 0.0);
    const double trace_opt = S0 + S1 + dsgn * S2;

    double msd = (sq - 2.0 * trace_opt) / n;
    if (msd < 0.0) msd = 0.0;
    out[b] = (float)sqrt(msd);
}

extern "C" void kernel_launch(void* const* d_in, const int* in_sizes, int n_in,
                              void* d_out, int out_size, void* d_ws, size_t ws_size,
                              hipStream_t stream) {
    const float* inp = (const float*)d_in[0];
    const float* tgt = (const float*)d_in[1];
    const int* num_atoms = (const int*)d_in[2];
    float* out = (float*)d_out;
    float* partial = (float*)d_ws;  // B*16 floats = 512 KB

    const int B = in_sizes[0] / FPE;
    const int blocks1 = (B + WPB - 1) / WPB;
    kabsch_reduce_kernel<<<blocks1, TPB, 0, stream>>>(inp, tgt, num_atoms, partial, B);
    const int blocks2 = (B + TPB - 1) / TPB;
    kabsch_epilogue_kernel<<<blocks2, TPB, 0, stream>>>(partial, num_atoms, out, B);
}